// Round 1
// baseline (401.036 us; speedup 1.0000x reference)
//
#include <hip/hip_runtime.h>
#include <math.h>

// Problem constants (img [8,64,112,112] f32, weights [64,64,3,3] f32, out [8,64,112,112] f32)
#define BATCH  8
#define CIN    64
#define HW     112
#define OUT_CH 64
#define KK     576     // CIN * 3 * 3
#define TX     16      // pixel tile width per block
#define TY     8       // pixel tile height per block
#define CHUNK  16      // input channels staged per LDS chunk
#define NCHUNK 4
#define ROWS   19      // padded LDS row stride (18 -> 4-way bank conflict; 19 -> ~2-way, free)

// ws layout (floats): [0 .. 36863] Wt[k][o] = W[o][k]; [36864 .. 36927] S[o] = sum_k W[o][k]
// needs ws_size >= 147,712 bytes.

__global__ void prep_kernel(const float* __restrict__ W, float* __restrict__ ws) {
    const int bid = blockIdx.x;
    const int t = threadIdx.x;
    if (bid < 144) {
        const int i = bid * 256 + t;      // i = k*64 + o, i < 36864
        const int o = i & 63;
        const int k = i >> 6;
        ws[i] = W[o * KK + k];
    } else if (t < OUT_CH) {
        float s = 0.f;
        for (int k = 0; k < KK; ++k) s += W[t * KK + k];
        ws[KK * OUT_CH + t] = s;
    }
}

__global__ __launch_bounds__(256) void conv_main(const float* __restrict__ img,
                                                 const float* __restrict__ ws,
                                                 float* __restrict__ out) {
    __shared__ float simg[CHUNK * 10 * ROWS];   // 3040 floats  = 12.16 KB
    __shared__ float swt[CHUNK * 9 * 64];       // 9216 floats  = 36.86 KB  (total 49 KB -> 3 blocks/CU)

    const int t = threadIdx.x;
    const int wave = t >> 6;            // 4 waves -> 4 groups of 16 output channels
    const int lane = t & 63;
    const int py = lane >> 3;           // 0..7
    const int px = (lane & 7) << 1;     // 0,2,..,14 (thread owns px, px+1)
    const int obase = wave << 4;

    const int bid = blockIdx.x;         // 784 blocks: 8 batches * 14 y-tiles * 7 x-tiles
    const int b = bid / 98;
    const int r = bid - b * 98;
    const int ty = r / 7;
    const int tx = r - ty * 7;
    const int y0 = ty * TY;
    const int x0 = tx * TX;

    float acc1[2][16], acc2[2][16], acc3[2][16];
    #pragma unroll
    for (int j = 0; j < 2; ++j)
        #pragma unroll
        for (int i = 0; i < 16; ++i) { acc1[j][i] = 0.f; acc2[j][i] = 0.f; acc3[j][i] = 0.f; }

    const float* imgb = img + (size_t)b * CIN * HW * HW;

    for (int cc = 0; cc < NCHUNK; ++cc) {
        // ---- stage weights: contiguous 9216 floats from Wt chunk, coalesced float4 ----
        const float4* wt4 = (const float4*)ws + cc * 2304;
        float4* swt4 = (float4*)swt;
        #pragma unroll
        for (int j = 0; j < 9; ++j) swt4[t + 256 * j] = wt4[t + 256 * j];

        // ---- stage img chunk: 16 channels x 10 x 18 (halo), zero-padded borders ----
        const int c0 = cc * CHUNK;
        for (int e = t; e < CHUNK * 180; e += 256) {
            const int c  = e / 180;
            const int rr = e - c * 180;
            const int ly = rr / 18;
            const int lx = rr - ly * 18;
            const int gy = y0 - 1 + ly;
            const int gx = x0 - 1 + lx;
            float v = 0.f;
            if ((unsigned)gy < HW && (unsigned)gx < HW)
                v = imgb[((c0 + c) * HW + gy) * HW + gx];
            simg[c * (10 * ROWS) + ly * ROWS + lx] = v;
        }
        __syncthreads();

        // ---- compute ----
        #pragma unroll 1
        for (int c = 0; c < CHUNK; ++c) {
            const float* sc = simg + c * (10 * ROWS);
            #pragma unroll
            for (int ky = 0; ky < 3; ++ky) {
                const float* srow = sc + (py + ky) * ROWS + px;
                float v[4], v2[4], v3[4];
                #pragma unroll
                for (int u = 0; u < 4; ++u) {
                    v[u] = srow[u]; v2[u] = v[u] * v[u]; v3[u] = v2[u] * v[u];
                }
                #pragma unroll
                for (int kx = 0; kx < 3; ++kx) {
                    const float* wp = swt + ((c * 9 + ky * 3 + kx) << 6) + obase;  // wave-uniform -> broadcast
                    const float4 wA = *(const float4*)(wp);
                    const float4 wB = *(const float4*)(wp + 4);
                    const float4 wC = *(const float4*)(wp + 8);
                    const float4 wD = *(const float4*)(wp + 12);
                    const float wv[16] = { wA.x, wA.y, wA.z, wA.w,  wB.x, wB.y, wB.z, wB.w,
                                           wC.x, wC.y, wC.z, wC.w,  wD.x, wD.y, wD.z, wD.w };
                    #pragma unroll
                    for (int i = 0; i < 16; ++i) {
                        const float w = wv[i];
                        acc1[0][i] += v[kx]      * w;  acc1[1][i] += v[kx + 1]  * w;
                        acc2[0][i] += v2[kx]     * w;  acc2[1][i] += v2[kx + 1] * w;
                        acc3[0][i] += v3[kx]     * w;  acc3[1][i] += v3[kx + 1] * w;
                    }
                }
            }
        }
        __syncthreads();
    }

    // ---- epilogue: f + 4 sigmoids + blend; write float2 per channel ----
    const float* S = ws + KK * OUT_CH;
    const int y = y0 + py;
    #pragma unroll
    for (int i = 0; i < 16; ++i) {
        const int o = obase + i;
        const float Sv = S[o];
        float res[2];
        #pragma unroll
        for (int j = 0; j < 2; ++j) {
            const float u1 = acc1[j][i], u2 = acc2[j][i], u3 = acc3[j][i];
            const float f = (-0.000287f * Sv + 0.266f * u1 - 0.1097f * u2) * (1.0f / 75.0f);
            const float g1 = (0.11f  * 576.0f / 75.0f) + 0.001309f  * Sv + 0.00619f   * u1 - 0.009f    * u2 + 0.001383f * u3;
            const float g2 = (0.179f * 576.0f / 75.0f) - 0.0025f    * Sv + 0.00303f   * u1 - 0.00484f  * u2 + 0.0175f   * u3;
            const float g3 = (0.238f * 576.0f / 75.0f) - 0.000954f  * Sv + 0.00187f   * u1 + 0.001877f * u2 + 0.01502f  * u3;
            const float g4 = (0.388f * 576.0f / 75.0f) - 0.00734f   * Sv + 0.001117f  * u1 + 0.00752f  * u2 + 0.009f    * u3;
            const float g5 = (0.507f * 576.0f / 75.0f) - 0.01017f   * Sv + 0.000426f  * u1 + 0.00837f  * u2 + 0.00413f  * u3;
            const float s1 = 1.0f / (1.0f + __expf(-10.0f * (f - 0.15f)));
            const float s2 = 1.0f / (1.0f + __expf(-10.0f * (f - 0.23f)));
            const float s3 = 1.0f / (1.0f + __expf(-10.0f * (f - 0.32f)));
            const float s4 = 1.0f / (1.0f + __expf(-10.0f * (f - 0.39f)));
            res[j] = g1 + s1 * (g2 - g1) + s2 * (g3 - g2) + s3 * (g4 - g3) + s4 * (g5 - g4);
        }
        float* op = out + (((size_t)(b * OUT_CH + o)) * HW + y) * HW + x0 + px;
        float2 st; st.x = res[0]; st.y = res[1];
        *(float2*)op = st;
    }
}

extern "C" void kernel_launch(void* const* d_in, const int* in_sizes, int n_in,
                              void* d_out, int out_size, void* d_ws, size_t ws_size,
                              hipStream_t stream) {
    const float* img = (const float*)d_in[0];
    const float* w   = (const float*)d_in[1];
    float* outp = (float*)d_out;
    float* ws   = (float*)d_ws;
    // prep: 144 blocks transpose W -> Wt[k][o], block 144 computes row sums S[o]
    hipLaunchKernelGGL(prep_kernel, dim3(145), dim3(256), 0, stream, w, ws);
    // main: 8 batches * 14 * 7 pixel tiles
    hipLaunchKernelGGL(conv_main, dim3(784), dim3(256), 0, stream, img, ws, outp);
}

// Round 2
// 141.472 us; speedup vs baseline: 2.8347x; 2.8347x over previous
//
#include <hip/hip_runtime.h>

#define HW   112
#define CIN  64
#define KK   576

typedef __attribute__((ext_vector_type(8))) short s16x8;
typedef __attribute__((ext_vector_type(4))) float f32x4;

__device__ inline unsigned short f2bf(float f) {
    unsigned u = __float_as_uint(f);
    u += 0x7FFF + ((u >> 16) & 1);            // RNE round to bf16
    return (unsigned short)(u >> 16);
}

// ws layout: [0 .. 73727] Wb (36864 bf16, MFMA-B fragment order); [73728 ..] S[64] fp32 row sums.
// Wb flat index: (((tap*2 + cc)*4 + nt)*64 + lane)*8 + j
//   k = cc*32 + (lane>>4)*8 + j  (input channel),  n = nt*16 + (lane&15)  (output channel)
//   value = W[n][k*9 + tap]
__global__ void prep_kernel(const float* __restrict__ W,
                            unsigned short* __restrict__ wb,
                            float* __restrict__ S) {
    __shared__ float partial[256];
    const int bid = blockIdx.x, t = threadIdx.x;
    if (bid < 144) {
        const int i   = bid * 256 + t;
        const int j   = i & 7;
        const int l   = (i >> 3) & 63;
        const int nt  = (i >> 9) & 3;
        const int cc  = (i >> 11) & 1;
        const int tap = i >> 12;
        const int c   = cc * 32 + ((l >> 4) << 3) + j;
        const int o   = nt * 16 + (l & 15);
        wb[i] = f2bf(W[o * KK + c * 9 + tap]);
    } else {
        const int o = t >> 2, part = t & 3;
        const float4* row = (const float4*)(W + o * KK) + part * 36;
        float s = 0.f;
        for (int k = 0; k < 36; ++k) { float4 v = row[k]; s += v.x + v.y + v.z + v.w; }
        partial[t] = s;
        __syncthreads();
        if (part == 0) S[o] = partial[t] + partial[t + 1] + partial[t + 2] + partial[t + 3];
    }
}

#define LROWS 6          // 4 output rows + 2 halo
#define LCOLS 18         // 16 output cols + 2 halo
#define CPAD  40         // 32 channels padded (20-word stride: 2-way banks = free; 80B keeps b128 aligned)
#define PSTRIDE (LROWS * LCOLS * CPAD)   // 4320 shorts per power image

__global__ __launch_bounds__(128, 3) void conv_main(const float* __restrict__ img,
                                                    const unsigned short* __restrict__ wb,
                                                    const float* __restrict__ S,
                                                    float* __restrict__ out) {
    __shared__ __align__(16) short tile[3 * PSTRIDE];   // 25.9 KB -> 6 blocks/CU

    const int t    = threadIdx.x;
    const int wv   = t >> 6;          // 2 waves: wave wv owns output rows {2wv, 2wv+1}
    const int lane = t & 63;
    const int m    = lane & 15;       // MFMA A: m = lane&15 (x within tile)
    const int q    = lane >> 4;       // quad: k = q*8 + j

    const int bid = blockIdx.x;       // 8 b * 28 ty * 7 tx = 1568
    const int b   = bid / 196;
    const int r   = bid - b * 196;
    const int ty  = r / 7;
    const int tx  = r - ty * 7;
    const int y0  = ty * 4, x0 = tx * 16;

    f32x4 acc[3][2][4];               // [power][m-tile][n-tile]
    #pragma unroll
    for (int p = 0; p < 3; ++p)
        #pragma unroll
        for (int at = 0; at < 2; ++at)
            #pragma unroll
            for (int nt = 0; nt < 4; ++nt)
                acc[p][at][nt] = (f32x4){0.f, 0.f, 0.f, 0.f};

    const float* imgb = img + (size_t)b * CIN * HW * HW;

    for (int cc = 0; cc < 2; ++cc) {
        if (cc) __syncthreads();
        // ---- stage 32 channels of v, v^2, v^3 as bf16, [y][x][c] layout ----
        const int c0 = cc * 32;
        for (int e = t; e < 32 * LROWS * LCOLS; e += 128) {   // 27 iters exactly
            const int c  = e / (LROWS * LCOLS);
            const int rr = e - c * (LROWS * LCOLS);
            const int y  = rr / LCOLS;
            const int x  = rr - y * LCOLS;
            const int gy = y0 - 1 + y, gx = x0 - 1 + x;
            float v = 0.f;
            if ((unsigned)gy < HW && (unsigned)gx < HW)
                v = imgb[((size_t)(c0 + c) * HW + gy) * HW + gx];
            const float v2 = v * v, v3 = v2 * v;
            const int base = (y * LCOLS + x) * CPAD + c;
            tile[base]               = (short)f2bf(v);
            tile[PSTRIDE + base]     = (short)f2bf(v2);
            tile[2 * PSTRIDE + base] = (short)f2bf(v3);
        }
        __syncthreads();

        // ---- K-loop: 9 taps x K=32 (this chunk's channels) ----
        #pragma unroll 3
        for (int tap = 0; tap < 9; ++tap) {
            const int ky = tap / 3, kx = tap - 3 * ky;
            s16x8 bf[4];
            const uint4* wbase = (const uint4*)wb + ((size_t)(tap * 2 + cc) * 4) * 64 + lane;
            #pragma unroll
            for (int nt = 0; nt < 4; ++nt)
                bf[nt] = *(const s16x8*)(wbase + nt * 64);
            #pragma unroll
            for (int at = 0; at < 2; ++at) {
                const int aoff = ((2 * wv + at + ky) * LCOLS + (m + kx)) * CPAD + q * 8;
                #pragma unroll
                for (int p = 0; p < 3; ++p) {
                    const s16x8 af = *(const s16x8*)&tile[p * PSTRIDE + aoff];
                    #pragma unroll
                    for (int nt = 0; nt < 4; ++nt)
                        acc[p][at][nt] = __builtin_amdgcn_mfma_f32_16x16x32_bf16(
                            af, bf[nt], acc[p][at][nt], 0, 0, 0);
                }
            }
        }
    }

    // ---- epilogue: D layout n = lane&15, pixel m = q*4 + reg ----
    #pragma unroll
    for (int nt = 0; nt < 4; ++nt) {
        const int o = nt * 16 + (lane & 15);
        const float Sv = S[o];
        const float fS = -0.000287f / 75.f * Sv;
        const float b1 = 0.8448f   + 0.001309f  * Sv;   // 0.11 *576/75
        const float b2 = 1.37472f  - 0.0025f    * Sv;   // 0.179*576/75
        const float b3 = 1.82784f  - 0.000954f  * Sv;   // 0.238*576/75
        const float b4 = 2.97984f  - 0.00734f   * Sv;   // 0.388*576/75
        const float b5 = 3.89376f  - 0.01017f   * Sv;   // 0.507*576/75
        #pragma unroll
        for (int at = 0; at < 2; ++at) {
            float res[4];
            #pragma unroll
            for (int rg = 0; rg < 4; ++rg) {
                const float u1 = acc[0][at][nt][rg];
                const float u2 = acc[1][at][nt][rg];
                const float u3 = acc[2][at][nt][rg];
                const float f  = fS + 0.00354667f * u1 - 0.00146267f * u2;  // 0.266/75, -0.1097/75
                const float g1 = b1 + 0.00619f  * u1 - 0.009f    * u2 + 0.001383f * u3;
                const float g2 = b2 + 0.00303f  * u1 - 0.00484f  * u2 + 0.0175f   * u3;
                const float g3 = b3 + 0.00187f  * u1 + 0.001877f * u2 + 0.01502f  * u3;
                const float g4 = b4 + 0.001117f * u1 + 0.00752f  * u2 + 0.009f    * u3;
                const float g5 = b5 + 0.000426f * u1 + 0.00837f  * u2 + 0.00413f  * u3;
                const float E  = __expf(-10.f * f);
                // sigma(10(f-c)) = 1/(1 + E*exp(10c))
                const float s1 = __builtin_amdgcn_rcpf(1.f + E * 4.4816890703f);
                const float s2 = __builtin_amdgcn_rcpf(1.f + E * 9.9741824548f);
                const float s3 = __builtin_amdgcn_rcpf(1.f + E * 24.5325301971f);
                const float s4 = __builtin_amdgcn_rcpf(1.f + E * 49.4024491055f);
                res[rg] = g1 + s1 * (g2 - g1) + s2 * (g3 - g2) + s3 * (g4 - g3) + s4 * (g5 - g4);
            }
            const int y = y0 + 2 * wv + at;
            float* op = out + (((size_t)(b * 64 + o)) * HW + y) * HW + x0 + q * 4;
            *(float4*)op = make_float4(res[0], res[1], res[2], res[3]);
        }
    }
}

extern "C" void kernel_launch(void* const* d_in, const int* in_sizes, int n_in,
                              void* d_out, int out_size, void* d_ws, size_t ws_size,
                              hipStream_t stream) {
    const float* img = (const float*)d_in[0];
    const float* w   = (const float*)d_in[1];
    float* outp = (float*)d_out;
    unsigned short* wb = (unsigned short*)d_ws;
    float* S = (float*)((char*)d_ws + 73728);
    hipLaunchKernelGGL(prep_kernel, dim3(145), dim3(256), 0, stream, w, wb, S);
    hipLaunchKernelGGL(conv_main, dim3(1568), dim3(128), 0, stream, img, wb, S, outp);
}

// Round 3
// 126.345 us; speedup vs baseline: 3.1741x; 1.1197x over previous
//
#include <hip/hip_runtime.h>

#define HW   112
#define PH   114            // padded plane dim
#define KK   576
#define PLANE_SH (8 * PH * PH * 64)        // shorts per power plane = 6,653,952 (13,307,904 B)
#define WB_OFF_SH (3 * PLANE_SH)           // weight frags start here
#define S_OFF_SH  (WB_OFF_SH + 36864)      // fp32 row sums (as 2 shorts each)
// ws_size needed: 3*13,307,904 + 73,728 + 256 = 39,997,696 B (~40 MB)

typedef __attribute__((ext_vector_type(8))) short s16x8;
typedef __attribute__((ext_vector_type(4))) float f32x4;
typedef __attribute__((address_space(3))) unsigned int lds_u32;
typedef const __attribute__((address_space(1))) unsigned int glb_u32;

__device__ inline unsigned short f2bf(float f) {
    unsigned u = __float_as_uint(f);
    u += 0x7FFF + ((u >> 16) & 1);            // RNE
    return (unsigned short)(u >> 16);
}

// ---- pass 1a: zero the 1-px borders of the three padded planes ----
__global__ void border_kernel(unsigned short* __restrict__ pw) {
    const int bid = blockIdx.x;              // 24 = 3p * 8b
    const int p = bid >> 3, b = bid & 7;
    unsigned short* base = pw + (size_t)p * PLANE_SH + (size_t)b * PH * PH * 64;
    const int t = threadIdx.x;
    const s16x8 z = {0, 0, 0, 0, 0, 0, 0, 0};
    for (int i = 0; i < 15; ++i) {
        const int e = t + i * 256;
        if (e >= 3616) break;                // 452 border px * 8 c-octs
        const int n = e >> 3, c8 = e & 7;
        int x, yy;
        if (n < 114)      { yy = 0;   x = n; }
        else if (n < 228) { yy = 113; x = n - 114; }
        else { const int m2 = n - 228; yy = 1 + (m2 >> 1); x = (m2 & 1) ? 113 : 0; }
        *(s16x8*)&base[(yy * PH + x) * 64 + c8 * 8] = z;
    }
}

// ---- pass 1b: NCHW fp32 -> padded NHWC bf16 planes of v, v^2, v^3 ----
__global__ __launch_bounds__(256) void pow_kernel(const float* __restrict__ img,
                                                  unsigned short* __restrict__ pw) {
    __shared__ __align__(16) unsigned short sA[3 * 112 * 72];   // [p][x][c pad 72] = 48.4 KB
    const int t = threadIdx.x;
    const int bid = blockIdx.x;              // 896 = 8b * 112y
    const int b = bid / 112, y = bid - b * 112;

    // phase A: read row (all c, all x) coalesced-ish, convert, LDS transpose
    const int c = t & 63, xq0 = t >> 6;
    const float4* src = (const float4*)(img + (((size_t)(b * 64 + c) * HW + y) * HW));
    #pragma unroll
    for (int i = 0; i < 7; ++i) {
        const int xq = xq0 + i * 4;
        const float4 v = src[xq];
        const float vv[4] = {v.x, v.y, v.z, v.w};
        #pragma unroll
        for (int u = 0; u < 4; ++u) {
            const float v1 = vv[u], v2 = v1 * v1, v3 = v2 * v1;
            const int x = xq * 4 + u;
            sA[x * 72 + c]         = f2bf(v1);
            sA[8064 + x * 72 + c]  = f2bf(v2);
            sA[16128 + x * 72 + c] = f2bf(v3);
        }
    }
    __syncthreads();

    // phase B: write interior rows, 16B chunks, fully coalesced
    for (int i = 0; i < 11; ++i) {
        const int ch = t + i * 256;
        if (ch >= 2688) break;               // 3p * 112x * 8 c-octs
        const int p = ch / 896, r = ch - p * 896;
        const int x = r >> 3, c8 = r & 7;
        const s16x8 val = *(const s16x8*)&sA[p * 8064 + x * 72 + c8 * 8];
        *(s16x8*)&pw[(size_t)p * PLANE_SH + ((size_t)(b * PH + y + 1) * PH + (x + 1)) * 64 + c8 * 8] = val;
    }
}

// ---- pass 1c: weights -> bf16 MFMA-B fragment order + row sums ----
// Wb flat index: (((tap*2 + cc)*4 + nt)*64 + lane)*8 + j
__global__ void prep_kernel(const float* __restrict__ W,
                            unsigned short* __restrict__ wb,
                            float* __restrict__ S) {
    __shared__ float partial[256];
    const int bid = blockIdx.x, t = threadIdx.x;
    if (bid < 144) {
        const int i   = bid * 256 + t;
        const int j   = i & 7;
        const int l   = (i >> 3) & 63;
        const int nt  = (i >> 9) & 3;
        const int cc  = (i >> 11) & 1;
        const int tap = i >> 12;
        const int c   = cc * 32 + ((l >> 4) << 3) + j;
        const int o   = nt * 16 + (l & 15);
        wb[i] = f2bf(W[o * KK + c * 9 + tap]);
    } else {
        const int o = t >> 2, part = t & 3;
        const float4* row = (const float4*)(W + o * KK) + part * 36;
        float s = 0.f;
        for (int k = 0; k < 36; ++k) { float4 v = row[k]; s += v.x + v.y + v.z + v.w; }
        partial[t] = s;
        __syncthreads();
        if (part == 0) S[o] = partial[t] + partial[t + 1] + partial[t + 2] + partial[t + 3];
    }
}

// ---- pass 2: implicit-GEMM conv, DMA staging, MFMA ----
// LDS tile: granule g = px*12 + p*4 + q (16B granules), px = y*18 + x over 6x18 halo tile
__global__ __launch_bounds__(128, 3) void conv_main(const unsigned short* __restrict__ pw,
                                                    const unsigned short* __restrict__ wb,
                                                    const float* __restrict__ S,
                                                    float* __restrict__ out) {
    __shared__ __align__(16) unsigned short tile[1296 * 8];   // 20,736 B

    const int t = threadIdx.x, wv = t >> 6, lane = t & 63;
    const int m = lane & 15, q = lane >> 4;

    const int bid = blockIdx.x;       // 1568: b = bid&7 (XCD pin), tile = bid>>3
    const int b = bid & 7;
    const int r = bid >> 3;           // 0..195
    const int ty = r / 7, tx = r - ty * 7;
    const int y0 = ty * 4, x0 = tx * 16;

    f32x4 acc[3][2][4];
    #pragma unroll
    for (int p = 0; p < 3; ++p)
        #pragma unroll
        for (int at = 0; at < 2; ++at)
            #pragma unroll
            for (int nt = 0; nt < 4; ++nt)
                acc[p][at][nt] = (f32x4){0.f, 0.f, 0.f, 0.f};

    const unsigned short* pbase = pw + ((size_t)(b * PH + y0) * PH + x0) * 64;

    for (int cc = 0; cc < 2; ++cc) {
        if (cc) __syncthreads();
        const int coff = cc * 32;
        // DMA: 1280 granules via global_load_lds, 16 tail granules via regular ld/st
        for (int i = 0; i < 10; ++i) {
            const int g = i * 128 + t;
            const int px = g / 12, rem = g - px * 12;
            const int pp = rem >> 2, qq = rem & 3;
            const int yy = px / 18, xx = px - yy * 18;
            const unsigned short* gp = pbase + (size_t)pp * PLANE_SH + (yy * PH + xx) * 64 + coff + qq * 8;
            lds_u32* lp = (lds_u32*)(unsigned short*)(tile + (size_t)(i * 128 + wv * 64) * 8);
            __builtin_amdgcn_global_load_lds((glb_u32*)gp, lp, 16, 0, 0);
        }
        if (t < 16) {
            const int g = 1280 + t;
            const int px = g / 12, rem = g - px * 12;
            const int pp = rem >> 2, qq = rem & 3;
            const int yy = px / 18, xx = px - yy * 18;
            const s16x8 v = *(const s16x8*)(pbase + (size_t)pp * PLANE_SH + (yy * PH + xx) * 64 + coff + qq * 8);
            *(s16x8*)&tile[g * 8] = v;
        }
        __syncthreads();

        #pragma unroll 3
        for (int tap = 0; tap < 9; ++tap) {
            const int ky = tap / 3, kx = tap - 3 * ky;
            s16x8 bf[4];
            const uint4* wbase = (const uint4*)wb + ((size_t)(tap * 2 + cc) * 4) * 64 + lane;
            #pragma unroll
            for (int nt = 0; nt < 4; ++nt)
                bf[nt] = *(const s16x8*)(wbase + nt * 64);
            #pragma unroll
            for (int at = 0; at < 2; ++at) {
                const int px = (2 * wv + at + ky) * 18 + m + kx;
                const int abase = px * 96 + q * 8;            // shorts; + p*32 per power
                #pragma unroll
                for (int p = 0; p < 3; ++p) {
                    const s16x8 af = *(const s16x8*)&tile[abase + p * 32];
                    #pragma unroll
                    for (int nt = 0; nt < 4; ++nt)
                        acc[p][at][nt] = __builtin_amdgcn_mfma_f32_16x16x32_bf16(
                            af, bf[nt], acc[p][at][nt], 0, 0, 0);
                }
            }
        }
    }

    // ---- epilogue: D layout n = lane&15, pixel m = q*4 + reg ----
    #pragma unroll
    for (int nt = 0; nt < 4; ++nt) {
        const int o = nt * 16 + (lane & 15);
        const float Sv = S[o];
        const float fS = -0.000287f / 75.f * Sv;
        const float b1 = 0.8448f   + 0.001309f  * Sv;
        const float b2 = 1.37472f  - 0.0025f    * Sv;
        const float b3 = 1.82784f  - 0.000954f  * Sv;
        const float b4 = 2.97984f  - 0.00734f   * Sv;
        const float b5 = 3.89376f  - 0.01017f   * Sv;
        #pragma unroll
        for (int at = 0; at < 2; ++at) {
            float res[4];
            #pragma unroll
            for (int rg = 0; rg < 4; ++rg) {
                const float u1 = acc[0][at][nt][rg];
                const float u2 = acc[1][at][nt][rg];
                const float u3 = acc[2][at][nt][rg];
                const float f  = fS + 0.00354667f * u1 - 0.00146267f * u2;
                const float g1 = b1 + 0.00619f  * u1 - 0.009f    * u2 + 0.001383f * u3;
                const float g2 = b2 + 0.00303f  * u1 - 0.00484f  * u2 + 0.0175f   * u3;
                const float g3 = b3 + 0.00187f  * u1 + 0.001877f * u2 + 0.01502f  * u3;
                const float g4 = b4 + 0.001117f * u1 + 0.00752f  * u2 + 0.009f    * u3;
                const float g5 = b5 + 0.000426f * u1 + 0.00837f  * u2 + 0.00413f  * u3;
                const float E  = __expf(-10.f * f);
                const float s1 = __builtin_amdgcn_rcpf(1.f + E * 4.4816890703f);
                const float s2 = __builtin_amdgcn_rcpf(1.f + E * 9.9741824548f);
                const float s3 = __builtin_amdgcn_rcpf(1.f + E * 24.5325301971f);
                const float s4 = __builtin_amdgcn_rcpf(1.f + E * 49.4024491055f);
                res[rg] = g1 + s1 * (g2 - g1) + s2 * (g3 - g2) + s3 * (g4 - g3) + s4 * (g5 - g4);
            }
            const int y = y0 + 2 * wv + at;
            float* op = out + (((size_t)(b * 64 + o)) * HW + y) * HW + x0 + q * 4;
            *(float4*)op = make_float4(res[0], res[1], res[2], res[3]);
        }
    }
}

extern "C" void kernel_launch(void* const* d_in, const int* in_sizes, int n_in,
                              void* d_out, int out_size, void* d_ws, size_t ws_size,
                              hipStream_t stream) {
    const float* img = (const float*)d_in[0];
    const float* w   = (const float*)d_in[1];
    float* outp = (float*)d_out;
    unsigned short* pw = (unsigned short*)d_ws;
    unsigned short* wb = pw + WB_OFF_SH;
    float* S = (float*)(pw + S_OFF_SH);

    hipLaunchKernelGGL(border_kernel, dim3(24),   dim3(256), 0, stream, pw);
    hipLaunchKernelGGL(pow_kernel,    dim3(896),  dim3(256), 0, stream, img, pw);
    hipLaunchKernelGGL(prep_kernel,   dim3(145),  dim3(256), 0, stream, w, wb, S);
    hipLaunchKernelGGL(conv_main,     dim3(1568), dim3(128), 0, stream, pw, wb, S, outp);
}